// Round 6
// baseline (513.121 us; speedup 1.0000x reference)
//
#include <hip/hip_runtime.h>
#include <math.h>

#define VOCAB 32000
#define NB 16        // batch
#define NH 12        // heads
#define DEC_T 128
#define ALEN 512
#define DD 768
#define NT 512       // threads per block
#define NW 8         // waves per block
#define V4 8000      // VOCAB/4 float4 per row
#define CHUNKS 16    // ceil(V4/NT)
#define HSZ 1024     // hash slots (pow2, >= 2*ALEN -> load factor <= 0.5)
#define HMASK (HSZ - 1)
#define BMW (VOCAB / 32)   // 1000 bitmap words
#define HEMPTY 0xFFFFFFFFu

__device__ inline float wave_sum(float v) {
#pragma unroll
  for (int o = 32; o > 0; o >>= 1) v += __shfl_down(v, o, 64);
  return v;
}
__device__ inline float wave_max(float v) {
#pragma unroll
  for (int o = 32; o > 0; o >>= 1) v = fmaxf(v, __shfl_down(v, o, 64));
  return v;
}

// 3-barrier restructure (was 10): every block-wide reduce is
// {wave partials -> barrier -> each thread folds the 8 partials itself};
// scatter stores RAW ae (ainv applied at read) so it needs no asum barrier.
__global__ __launch_bounds__(NT, 4) void pg_kernel(
    const float* __restrict__ dec, const float* __restrict__ fo,
    const float* __restrict__ attnw, const int* __restrict__ ids,
    const float* __restrict__ Wpg, const float* __restrict__ bpg,
    float* __restrict__ out) {
  __shared__ unsigned s_bm[BMW];     // presence bitmap, 4000 B
  __shared__ unsigned s_key[HSZ];    // hash keys, 4096 B
  __shared__ float    s_val[HSZ];    // hash values (raw ae sums), 4096 B
  __shared__ float    s_redA[NW];    // attn max partials
  __shared__ float    s_redB[NW];    // pgen dot partials
  __shared__ float    s_redC[NW];    // ae sum partials
  __shared__ float    s_redD[NW];    // row max partials
  __shared__ float    s_redE[NW];    // Z partials

  const int bt = blockIdx.x;          // b*DEC_T + t
  const int b = bt / DEC_T;
  const int t = bt - b * DEC_T;
  const int tid = threadIdx.x;
  const int lane = tid & 63;
  const int wid = tid >> 6;

  // ---------- phase 1: small loads FIRST (attn 12, dec 2, ids 1) ----------
  // Their in-order vmcnt retirement must not queue behind the 128 KB row.
  const float* ap = attnw + ((size_t)b * NH * DEC_T + t) * ALEN + tid;
  float hsum = 0.f;
#pragma unroll
  for (int h = 0; h < NH; ++h) hsum += ap[(size_t)h * DEC_T * ALEN];
  float pp = dec[(size_t)bt * DD + tid] * Wpg[tid];
  if (tid < DD - NT) pp += dec[(size_t)bt * DD + NT + tid] * Wpg[NT + tid];
  const unsigned myid = (unsigned)ids[b * ALEN + tid];   // ALEN == NT

  // row prefetch: issued after the small loads, in flight through phase 1/2
  const float4* row4 = (const float4*)(fo + (size_t)bt * VOCAB);
  float4 r[CHUNKS];
#pragma unroll
  for (int c = 0; c < CHUNKS; ++c) {
    int idx = c * NT + tid;           // only c==15 is conditional (tid<320)
    if (idx < V4) r[c] = row4[idx];
  }

  // zero scatter structures
  for (int i = tid; i < BMW; i += NT) s_bm[i] = 0u;
  for (int i = tid; i < HSZ; i += NT) { s_key[i] = HEMPTY; s_val[i] = 0.f; }

  const float amean = hsum * (1.f / NH);
  float am = wave_max(amean);
  if (lane == 0) s_redA[wid] = am;
  pp = wave_sum(pp);
  if (lane == 0) s_redB[wid] = pp;
  __syncthreads();                                     // B1

  // ---------- phase 2: amax/pgen broadcast; ae; scatter raw; row max ----------
  float amax = -INFINITY, pdot = 0.f;
#pragma unroll
  for (int i = 0; i < NW; ++i) {
    amax = fmaxf(amax, s_redA[i]);
    pdot += s_redB[i];
  }
  const float pgen = 1.f / (1.f + __expf(-(pdot + bpg[0])));
  const float ae = __expf(amean - amax);
  float as = wave_sum(ae);
  if (lane == 0) s_redC[wid] = as;

  // scatter RAW ae; duplicates merged by atomicAdd; ainv applied at read
  atomicOr(&s_bm[myid >> 5], 1u << (myid & 31));
  {
    unsigned h = (myid * 2654435761u) >> 22;   // top 10 bits of Knuth hash
    for (;;) {
      unsigned old = atomicCAS(&s_key[h], HEMPTY, myid);
      if (old == HEMPTY || old == myid) { atomicAdd(&s_val[h], ae); break; }
      h = (h + 1) & HMASK;                     // <=512 entries in 1024 slots
    }
  }

  float m = -INFINITY;
#pragma unroll
  for (int c = 0; c < CHUNKS; ++c) {
    int idx = c * NT + tid;
    if (idx < V4)
      m = fmaxf(m, fmaxf(fmaxf(r[c].x, r[c].y), fmaxf(r[c].z, r[c].w)));
  }
  m = wave_max(m);
  if (lane == 0) s_redD[wid] = m;
  __syncthreads();                                     // B2

  // ---------- phase 3: asum/fm broadcast; Z partials ----------
  float asum = 0.f, fm = -INFINITY;
#pragma unroll
  for (int i = 0; i < NW; ++i) {
    asum += s_redC[i];
    fm = fmaxf(fm, s_redD[i]);
  }
  const float ainv = (1.f - pgen) / asum;
  float zs = 0.f;
#pragma unroll
  for (int c = 0; c < CHUNKS; ++c) {
    int idx = c * NT + tid;
    if (idx < V4)
      zs += __expf(r[c].x - fm) + __expf(r[c].y - fm) +
            __expf(r[c].z - fm) + __expf(r[c].w - fm);
  }
  zs = wave_sum(zs);
  if (lane == 0) s_redE[wid] = zs;
  __syncthreads();                                     // B3 (also publishes scatter)

  // ---------- phase 4: Z/C broadcast; output ----------
  float Z = 0.f;
#pragma unroll
  for (int i = 0; i < NW; ++i) Z += s_redE[i];
  const float invZ = 1.f / Z;
  const float C = __logf(pgen) - fm - __logf(Z);

  auto hget = [&](unsigned id) -> float {
    unsigned h = (id * 2654435761u) >> 22;
    while (s_key[h] != id) h = (h + 1) & HMASK;  // bitmap bit set => present
    return s_val[h];
  };

  // scatter==0 (the common case, ~98.4%): x + C  (no exp/log, 1 bitmap word)
  float4* out4 = (float4*)(out + (size_t)bt * VOCAB);
#pragma unroll
  for (int c = 0; c < CHUNKS; ++c) {
    int idx = c * NT + tid;
    if (idx < V4) {
      const float4 x = r[c];
      float4 o;
      const unsigned nib = (s_bm[idx >> 3] >> ((idx & 7) * 4)) & 0xFu;
      if (nib == 0u) {
        o.x = x.x + C; o.y = x.y + C; o.z = x.z + C; o.w = x.w + C;
      } else {
        const unsigned v = (unsigned)idx * 4u;
        o.x = (nib & 1u) ? __logf(pgen * __expf(x.x - fm) * invZ + hget(v + 0u) * ainv) : (x.x + C);
        o.y = (nib & 2u) ? __logf(pgen * __expf(x.y - fm) * invZ + hget(v + 1u) * ainv) : (x.y + C);
        o.z = (nib & 4u) ? __logf(pgen * __expf(x.z - fm) * invZ + hget(v + 2u) * ainv) : (x.z + C);
        o.w = (nib & 8u) ? __logf(pgen * __expf(x.w - fm) * invZ + hget(v + 3u) * ainv) : (x.w + C);
      }
      out4[idx] = o;
    }
  }
}

extern "C" void kernel_launch(void* const* d_in, const int* in_sizes, int n_in,
                              void* d_out, int out_size, void* d_ws, size_t ws_size,
                              hipStream_t stream) {
  (void)in_sizes; (void)n_in; (void)out_size; (void)d_ws; (void)ws_size;
  const float* dec   = (const float*)d_in[0];   // (16,128,768)
  const float* fo    = (const float*)d_in[1];   // (16,128,32000)
  const float* attnw = (const float*)d_in[2];   // (16,12,128,512)
  const int*   ids   = (const int*)  d_in[3];   // (16,512)
  const float* Wpg   = (const float*)d_in[4];   // (768,1)
  const float* bpg   = (const float*)d_in[5];   // (1,)
  float* out = (float*)d_out;                   // (16,128,32000)

  pg_kernel<<<NB * DEC_T, NT, 0, stream>>>(dec, fo, attnw, ids, Wpg, bpg, out);
}

// Round 7
// 476.027 us; speedup vs baseline: 1.0779x; 1.0779x over previous
//
#include <hip/hip_runtime.h>
#include <math.h>

#define VOCAB 32000
#define NB 16        // batch
#define NH 12        // heads
#define DEC_T 128
#define ALEN 512
#define DD 768
#define NT 512       // threads per block
#define NW 8         // waves per block
#define V4 8000      // VOCAB/4 float4 per row
#define CHUNKS 16    // ceil(V4/NT)
#define HSZ 1024     // hash slots (pow2, >= 2*ALEN -> load factor <= 0.5)
#define HMASK (HSZ - 1)
#define BMW (VOCAB / 32)   // 1000 bitmap words
#define HEMPTY 0xFFFFFFFFu

__device__ inline float wave_sum(float v) {
#pragma unroll
  for (int o = 32; o > 0; o >>= 1) v += __shfl_down(v, o, 64);
  return v;
}
__device__ inline float wave_max(float v) {
#pragma unroll
  for (int o = 32; o > 0; o >>= 1) v = fmaxf(v, __shfl_down(v, o, 64));
  return v;
}

// launch_bounds(NT,2): VGPR cap 256 so the r[16] row cache stays in registers.
// (R6 evidence: cap 128 -> allocator budgeted 64 and spilled ~125 MB to scratch.)
// Online (m,Z) softmax over the row runs BEFORE the first barrier so the
// 64-exp Z pass overlaps row-load retirement; 2 barriers total.
__global__ __launch_bounds__(NT, 2) void pg_kernel(
    const float* __restrict__ dec, const float* __restrict__ fo,
    const float* __restrict__ attnw, const int* __restrict__ ids,
    const float* __restrict__ Wpg, const float* __restrict__ bpg,
    float* __restrict__ out) {
  __shared__ unsigned s_bm[BMW];     // presence bitmap, 4000 B
  __shared__ unsigned s_key[HSZ];    // hash keys, 4096 B
  __shared__ float    s_val[HSZ];    // hash values (raw ae sums), 4096 B
  __shared__ float    s_redA[NW];    // attn max partials
  __shared__ float    s_redB[NW];    // pgen dot partials
  __shared__ float    s_redC[NW];    // ae sum partials
  __shared__ float    s_redM[NW];    // row online max partials
  __shared__ float    s_redZ[NW];    // row online Z partials

  const int bt = blockIdx.x;          // b*DEC_T + t
  const int b = bt / DEC_T;
  const int t = bt - b * DEC_T;
  const int tid = threadIdx.x;
  const int lane = tid & 63;
  const int wid = tid >> 6;

  // ---------- barrier-free phase A ----------
  // small loads first (in-order vmcnt retirement: they come back before the row)
  const float* ap = attnw + ((size_t)b * NH * DEC_T + t) * ALEN + tid;
  float hsum = 0.f;
#pragma unroll
  for (int h = 0; h < NH; ++h) hsum += ap[(size_t)h * DEC_T * ALEN];
  float pp = dec[(size_t)bt * DD + tid] * Wpg[tid];
  if (tid < DD - NT) pp += dec[(size_t)bt * DD + NT + tid] * Wpg[NT + tid];
  const unsigned myid = (unsigned)ids[b * ALEN + tid];   // ALEN == NT

  // row loads (128 KB), in flight through all of phase A
  const float4* row4 = (const float4*)(fo + (size_t)bt * VOCAB);
  float4 r[CHUNKS];
#pragma unroll
  for (int c = 0; c < CHUNKS; ++c) {
    int idx = c * NT + tid;           // only c==15 is conditional (tid<320)
    if (idx < V4) r[c] = row4[idx];
  }

  // zero scatter structures (LDS-only, overlaps load latency)
  for (int i = tid; i < BMW; i += NT) s_bm[i] = 0u;
  for (int i = tid; i < HSZ; i += NT) { s_key[i] = HEMPTY; s_val[i] = 0.f; }

  // attn / pgen wave partials (depend only on the small loads)
  const float amean = hsum * (1.f / NH);
  float am = wave_max(amean);
  if (lane == 0) s_redA[wid] = am;
  pp = wave_sum(pp);
  if (lane == 0) s_redB[wid] = pp;

  // online (m, Z) over the row: chunk c's exps overlap retirement of c+1..15
  float m = -INFINITY, Zt = 0.f;
#pragma unroll
  for (int c = 0; c < CHUNKS; ++c) {
    int idx = c * NT + tid;
    if (idx < V4) {
      const float4 x = r[c];
      const float cm = fmaxf(fmaxf(x.x, x.y), fmaxf(x.z, x.w));
      const float m2 = fmaxf(m, cm);
      Zt = Zt * __expf(m - m2) + __expf(x.x - m2) + __expf(x.y - m2) +
           __expf(x.z - m2) + __expf(x.w - m2);
      m = m2;
    }
  }
  // joint wave reduction of (m, Z) with rescale
#pragma unroll
  for (int o = 32; o > 0; o >>= 1) {
    const float mo = __shfl_down(m, o, 64);
    const float zo = __shfl_down(Zt, o, 64);
    const float m2 = fmaxf(m, mo);
    Zt = Zt * __expf(m - m2) + zo * __expf(mo - m2);
    m = m2;
  }
  if (lane == 0) { s_redM[wid] = m; s_redZ[wid] = Zt; }
  __syncthreads();                                     // B1

  // ---------- phase B: folds; ae; scatter ----------
  float amax = -INFINITY, pdot = 0.f, fm = -INFINITY;
#pragma unroll
  for (int i = 0; i < NW; ++i) {
    amax = fmaxf(amax, s_redA[i]);
    pdot += s_redB[i];
    fm = fmaxf(fm, s_redM[i]);
  }
  float Z = 0.f;
#pragma unroll
  for (int i = 0; i < NW; ++i) Z += s_redZ[i] * __expf(s_redM[i] - fm);

  const float pgen = 1.f / (1.f + __expf(-(pdot + bpg[0])));
  const float ae = __expf(amean - amax);
  float as = wave_sum(ae);
  if (lane == 0) s_redC[wid] = as;

  // scatter RAW ae (ainv applied at read); duplicates merged by atomicAdd
  atomicOr(&s_bm[myid >> 5], 1u << (myid & 31));
  {
    unsigned h = (myid * 2654435761u) >> 22;   // top 10 bits of Knuth hash
    for (;;) {
      unsigned old = atomicCAS(&s_key[h], HEMPTY, myid);
      if (old == HEMPTY || old == myid) { atomicAdd(&s_val[h], ae); break; }
      h = (h + 1) & HMASK;                     // <=512 entries in 1024 slots
    }
  }
  __syncthreads();                                     // B2

  // ---------- phase C: output ----------
  float asum = 0.f;
#pragma unroll
  for (int i = 0; i < NW; ++i) asum += s_redC[i];
  const float ainv = (1.f - pgen) / asum;
  const float invZ = 1.f / Z;
  const float C = __logf(pgen) - fm - __logf(Z);

  auto hget = [&](unsigned id) -> float {
    unsigned h = (id * 2654435761u) >> 22;
    while (s_key[h] != id) h = (h + 1) & HMASK;  // bitmap bit set => present
    return s_val[h];
  };

  // scatter==0 (the common case, ~98.4%): x + C  (no exp/log, 1 bitmap word)
  float4* out4 = (float4*)(out + (size_t)bt * VOCAB);
#pragma unroll
  for (int c = 0; c < CHUNKS; ++c) {
    int idx = c * NT + tid;
    if (idx < V4) {
      const float4 x = r[c];
      float4 o;
      const unsigned nib = (s_bm[idx >> 3] >> ((idx & 7) * 4)) & 0xFu;
      if (nib == 0u) {
        o.x = x.x + C; o.y = x.y + C; o.z = x.z + C; o.w = x.w + C;
      } else {
        const unsigned v = (unsigned)idx * 4u;
        o.x = (nib & 1u) ? __logf(pgen * __expf(x.x - fm) * invZ + hget(v + 0u) * ainv) : (x.x + C);
        o.y = (nib & 2u) ? __logf(pgen * __expf(x.y - fm) * invZ + hget(v + 1u) * ainv) : (x.y + C);
        o.z = (nib & 4u) ? __logf(pgen * __expf(x.z - fm) * invZ + hget(v + 2u) * ainv) : (x.z + C);
        o.w = (nib & 8u) ? __logf(pgen * __expf(x.w - fm) * invZ + hget(v + 3u) * ainv) : (x.w + C);
      }
      out4[idx] = o;
    }
  }
}

extern "C" void kernel_launch(void* const* d_in, const int* in_sizes, int n_in,
                              void* d_out, int out_size, void* d_ws, size_t ws_size,
                              hipStream_t stream) {
  (void)in_sizes; (void)n_in; (void)out_size; (void)d_ws; (void)ws_size;
  const float* dec   = (const float*)d_in[0];   // (16,128,768)
  const float* fo    = (const float*)d_in[1];   // (16,128,32000)
  const float* attnw = (const float*)d_in[2];   // (16,12,128,512)
  const int*   ids   = (const int*)  d_in[3];   // (16,512)
  const float* Wpg   = (const float*)d_in[4];   // (768,1)
  const float* bpg   = (const float*)d_in[5];   // (1,)
  float* out = (float*)d_out;                   // (16,128,32000)

  pg_kernel<<<NB * DEC_T, NT, 0, stream>>>(dec, fo, attnw, ids, Wpg, bpg, out);
}